// Round 5
// baseline (225.571 us; speedup 1.0000x reference)
//
#include <hip/hip_runtime.h>

// OPT attention: B=16 T=4 E=2048 H=32 HD=64 P=4096 S=4100, M=B*T=64 rows.
// R5: latency attack — explicit depth-2 register pipelines in GEMMs (24 loads
// in flight/wave), k_flash 1-barrier wave-owns-rows softmax, Opart bf16.
// MFMA mfma_f32_16x16x32_bf16: A[m=lane&15][k=quad*8+j], B[n=lane&15][k=quad*8+j],
// D col=lane&15, row=quad*4+reg (verified layouts). Output dtype: f32.

typedef float f4 __attribute__((ext_vector_type(4)));
typedef short s8v __attribute__((ext_vector_type(8)));

#define NEG_HUGE (-3.402823466e38f)

__device__ inline unsigned short f2bs(float x) {  // f32 -> bf16 bits (RNE)
  union { float f; unsigned int u; } a; a.f = x;
  unsigned int u = a.u;
  u += 0x7fffu + ((u >> 16) & 1u);
  return (unsigned short)(u >> 16);
}
__device__ inline float bs2f(unsigned short s) {
  union { unsigned int u; float f; } a; a.u = ((unsigned int)s) << 16;
  return a.f;
}
__device__ inline s8v cvt8(f4 a, f4 b) {
  s8v r;
  r[0]=(short)f2bs(a[0]); r[1]=(short)f2bs(a[1]); r[2]=(short)f2bs(a[2]); r[3]=(short)f2bs(a[3]);
  r[4]=(short)f2bs(b[0]); r[5]=(short)f2bs(b[1]); r[6]=(short)f2bs(b[2]); r[7]=(short)f2bs(b[3]);
  return r;
}
__device__ inline f4 mfma16(s8v a, s8v b, f4 c) {
  return __builtin_amdgcn_mfma_f32_16x16x32_bf16(a, b, c, 0, 0, 0);
}
__device__ inline f4 fzero() { f4 z = {0.f,0.f,0.f,0.f}; return z; }

// ---------------- Kernel 0: hs f32 -> bf16 [64][2048] ------------------------
__global__ __launch_bounds__(256) void k_hs2bf(
    const float* __restrict__ hs, unsigned short* __restrict__ hsb) {
  const int i = (blockIdx.x * 256 + threadIdx.x) * 8;   // 16384 threads
  f4 a0 = *reinterpret_cast<const f4*>(hs + i);
  f4 a1 = *reinterpret_cast<const f4*>(hs + i + 4);
  *reinterpret_cast<s8v*>(hsb + i) = cvt8(a0, a1);
}

// ---------- Kernel 1: QKV projection, in-block K-split-4, reg pipeline -------
// grid 768: n-tile = bx>>1 (16 cols), m-half = bx&1. 8 waves: mt=w&1, kq=w>>1.
// Per wave K=512 = 4 chunks of 128; depth-2 prefetch (24 loads in flight).
__global__ __launch_bounds__(512, 4) void k_qkvp(
    const unsigned short* __restrict__ hsb, const float* __restrict__ Wq,
    const float* __restrict__ Wk, const float* __restrict__ Wv,
    const float* __restrict__ bq, const float* __restrict__ bk,
    const float* __restrict__ bv, unsigned short* __restrict__ qws,
    float* __restrict__ knew, float* __restrict__ vnew) {
  __shared__ float red[6][16][17];
  const int n0 = (blockIdx.x >> 1) * 16;
  const int mh = blockIdx.x & 1;
  const int p = n0 >> 11;                 // 0:q 1:k 2:v
  const int c0 = n0 & 2047;
  const float* W = (p == 0) ? Wq : (p == 1) ? Wk : Wv;
  const float* bias = (p == 0) ? bq : (p == 1) ? bk : bv;
  const int t = threadIdx.x, lane = t & 63, w = t >> 6;
  const int mt = w & 1, kq = w >> 1;
  const int cl = lane & 15, q = lane >> 4;
  const int rbase = mh * 32 + mt * 16;

  const unsigned short* arow = hsb + (rbase + cl) * 2048 + kq * 512 + q * 8;
  const float* brow = W + (size_t)(c0 + cl) * 2048 + kq * 512 + q * 8;

  s8v ab[2][4];
  f4 bb[2][8];
  auto loadc = [&](int s, int c) {
    const unsigned short* ap = arow + c * 128;
    const float* bp = brow + c * 128;
    #pragma unroll
    for (int i = 0; i < 4; ++i) {
      ab[s][i] = *reinterpret_cast<const s8v*>(ap + i * 32);
      bb[s][2 * i]     = *reinterpret_cast<const f4*>(bp + i * 32);
      bb[s][2 * i + 1] = *reinterpret_cast<const f4*>(bp + i * 32 + 4);
    }
  };
  f4 acc = fzero();
  loadc(0, 0);
  loadc(1, 1);
  #pragma unroll
  for (int c = 0; c < 4; ++c) {
    const int s = c & 1;
    s8v a0 = ab[s][0], a1 = ab[s][1], a2 = ab[s][2], a3 = ab[s][3];
    f4 b0 = bb[s][0], b1 = bb[s][1], b2 = bb[s][2], b3 = bb[s][3];
    f4 b4 = bb[s][4], b5 = bb[s][5], b6 = bb[s][6], b7 = bb[s][7];
    if (c < 2) loadc(s, c + 2);
    acc = mfma16(a0, cvt8(b0, b1), acc);
    acc = mfma16(a1, cvt8(b2, b3), acc);
    acc = mfma16(a2, cvt8(b4, b5), acc);
    acc = mfma16(a3, cvt8(b6, b7), acc);
  }
  if (kq) {
    #pragma unroll
    for (int rg = 0; rg < 4; ++rg) red[(kq - 1) * 2 + mt][q * 4 + rg][cl] = acc[rg];
  }
  __syncthreads();
  if (kq == 0) {
    const int c = c0 + cl, h = c >> 6, d = c & 63;
    #pragma unroll
    for (int rg = 0; rg < 4; ++rg) {
      const int rr = q * 4 + rg;
      const int r = rbase + rr;           // global row (b*4+t)
      const int b = r >> 2, tt = r & 3;
      float v = acc[rg] + red[mt][rr][cl] + red[2 + mt][rr][cl]
              + red[4 + mt][rr][cl] + bias[c];
      if (p == 0) {
        qws[h * 4608 + r * 72 + d] = f2bs(v * 0.125f);
      } else if (p == 1) {
        knew[((h * 16 + b) * 4 + tt) * 64 + d] = v;
      } else {
        vnew[((h * 16 + b) * 4 + tt) * 64 + d] = v;
      }
    }
  }
}

// --------- Kernel 2: flash partial attention, 128-pos chunks, 1 barrier ------
// grid 1024: h = bx&31, chunk = bx>>5. Wave w owns rows w*16..w*16+15 for QK^T
// (all 128 cols -> softmax is pure in-wave shuffle), d-tile w for PV.
__global__ __launch_bounds__(256, 4) void k_flash(
    const unsigned short* __restrict__ qws, const float* __restrict__ Kp,
    const float* __restrict__ Vp, const float* __restrict__ mask,
    unsigned short* __restrict__ Opart, float* __restrict__ mpart,
    float* __restrict__ lpart) {
  __shared__ __align__(16) unsigned short Pb[64 * 136];   // P bf16
  __shared__ __align__(16) unsigned short Vb[128 * 74];   // V bf16
  const int bx = blockIdx.x;
  const int h = bx & 31, cch = bx >> 5;                   // cch in [0,32)
  const int s0 = cch * 128;
  const int t = threadIdx.x, lane = t & 63, w = t >> 6;
  const int cl = lane & 15, q = lane >> 4;
  const float* Kh = Kp + (size_t)h * 4096 * 64;
  const float* Vh = Vp + (size_t)h * 4096 * 64;

  // V chunk loads (issued early; converted/stored to LDS below)
  f4 vreg[8];
  #pragma unroll
  for (int i = 0; i < 8; ++i) {
    int idx = t + i * 256;                 // 0..2047 float4s
    int s = idx >> 4, d4 = (idx & 15) << 2;
    vreg[i] = *reinterpret_cast<const f4*>(Vh + (size_t)(s0 + s) * 64 + d4);
  }

  // Q fragments for rows w*16..w*16+15
  s8v afr[2];
  #pragma unroll
  for (int k2 = 0; k2 < 2; ++k2)
    afr[k2] = *reinterpret_cast<const s8v*>(
        qws + h * 4608 + (w * 16 + cl) * 72 + k2 * 32 + q * 8);

  // QK^T: all 8 col-tiles for this wave's 16 rows (K re-read x4 waves -> L1)
  f4 sc[8];
  #pragma unroll
  for (int ni = 0; ni < 8; ++ni) {
    sc[ni] = fzero();
    const float* kr = Kh + (size_t)(s0 + ni * 16 + cl) * 64 + q * 8;
    #pragma unroll
    for (int k2 = 0; k2 < 2; ++k2) {
      f4 k0v = *reinterpret_cast<const f4*>(kr + k2 * 32);
      f4 k1v = *reinterpret_cast<const f4*>(kr + k2 * 32 + 4);
      sc[ni] = mfma16(afr[k2], cvt8(k0v, k1v), sc[ni]);
    }
  }

  // V -> bf16 LDS [128][74]
  {
    unsigned int* Vb32 = reinterpret_cast<unsigned int*>(Vb);
    #pragma unroll
    for (int i = 0; i < 8; ++i) {
      int idx = t + i * 256;
      int s = idx >> 4, d4 = (idx & 15) << 2;
      f4 v = vreg[i];
      unsigned int lo = (unsigned int)f2bs(v[0]) | ((unsigned int)f2bs(v[1]) << 16);
      unsigned int hi = (unsigned int)f2bs(v[2]) | ((unsigned int)f2bs(v[3]) << 16);
      int u = s * 37 + (d4 >> 1);
      Vb32[u] = lo; Vb32[u + 1] = hi;
    }
  }

  // mask add + row max (in-lane over ni, then shuffle over cl)
  float mx[4] = {NEG_HUGE, NEG_HUGE, NEG_HUGE, NEG_HUGE};
  #pragma unroll
  for (int rg = 0; rg < 4; ++rg) {
    const int r = w * 16 + q * 4 + rg;
    #pragma unroll
    for (int ni = 0; ni < 8; ++ni) {
      float v = sc[ni][rg] + mask[(size_t)r * 4100 + s0 + ni * 16 + cl];
      v = fmaxf(v, NEG_HUGE);
      sc[ni][rg] = v;
      mx[rg] = fmaxf(mx[rg], v);
    }
  }
  #pragma unroll
  for (int rg = 0; rg < 4; ++rg) {
    #pragma unroll
    for (int off = 1; off < 16; off <<= 1)
      mx[rg] = fmaxf(mx[rg], __shfl_xor(mx[rg], off, 64));
  }
  if (cl == 0) {
    #pragma unroll
    for (int rg = 0; rg < 4; ++rg)
      mpart[(h * 32 + cch) * 64 + w * 16 + q * 4 + rg] = mx[rg];
  }
  // exp (in regs) + row sums + P -> LDS bf16
  float sm[4] = {0.f, 0.f, 0.f, 0.f};
  #pragma unroll
  for (int rg = 0; rg < 4; ++rg) {
    const int r = w * 16 + q * 4 + rg;
    #pragma unroll
    for (int ni = 0; ni < 8; ++ni) {
      float e = __expf(sc[ni][rg] - mx[rg]);
      sm[rg] += e;
      Pb[r * 136 + ni * 16 + cl] = f2bs(e);
    }
  }
  #pragma unroll
  for (int rg = 0; rg < 4; ++rg) {
    #pragma unroll
    for (int off = 1; off < 16; off <<= 1)
      sm[rg] += __shfl_xor(sm[rg], off, 64);
  }
  if (cl == 0) {
    #pragma unroll
    for (int rg = 0; rg < 4; ++rg)
      lpart[(h * 32 + cch) * 64 + w * 16 + q * 4 + rg] = sm[rg];
  }
  __syncthreads();   // the only barrier: Vb + Pb ready

  // PV: wave w owns d-cols w*16..w*16+15
  f4 oacc[4];
  #pragma unroll
  for (int mt = 0; mt < 4; ++mt) oacc[mt] = fzero();
  const int dcol = w * 16 + cl;
  #pragma unroll
  for (int k2 = 0; k2 < 4; ++k2) {
    const int sb = k2 * 32 + q * 8;
    s8v bf;
    #pragma unroll
    for (int j = 0; j < 8; ++j) bf[j] = (short)Vb[(sb + j) * 74 + dcol];
    #pragma unroll
    for (int mt = 0; mt < 4; ++mt) {
      s8v pa = *reinterpret_cast<const s8v*>(&Pb[(mt * 16 + cl) * 136 + sb]);
      oacc[mt] = mfma16(pa, bf, oacc[mt]);
    }
  }
  unsigned short* ob = Opart + (size_t)(h * 32 + cch) * 4096;
  #pragma unroll
  for (int mt = 0; mt < 4; ++mt)
    #pragma unroll
    for (int rg = 0; rg < 4; ++rg)
      ob[(mt * 16 + q * 4 + rg) * 64 + dcol] = f2bs(oacc[mt][rg]);
}

// ------- Kernel 3: merge 32 chunk partials + 4 new-token scores --------------
// grid 512 x 256 threads: d = t&63, token tt = t>>6 (one wave per token)
__global__ __launch_bounds__(256) void k_merge(
    const unsigned short* __restrict__ qws, const float* __restrict__ knew,
    const float* __restrict__ vnew, const float* __restrict__ mask,
    const unsigned short* __restrict__ Opart, const float* __restrict__ mpart,
    const float* __restrict__ lpart, unsigned short* __restrict__ attn) {
  const int bx = blockIdx.x;
  const int h = bx & 31, b = bx >> 5;
  const int d = threadIdx.x & 63, tt = threadIdx.x >> 6;
  const int r = b * 4 + tt;
  float qd = bs2f(qws[h * 4608 + r * 72 + d]);
  float scn[4];
  #pragma unroll
  for (int tp = 0; tp < 4; ++tp) {
    float kn = knew[((h * 16 + b) * 4 + tp) * 64 + d];
    float s = qd * kn;
    #pragma unroll
    for (int off = 32; off; off >>= 1) s += __shfl_xor(s, off, 64);
    s += mask[(size_t)r * 4100 + 4096 + tp];
    scn[tp] = fmaxf(s, NEG_HUGE);
  }
  float mi[32], li[32];
  float mtot = NEG_HUGE;
  #pragma unroll
  for (int i = 0; i < 32; ++i) {
    mi[i] = mpart[(h * 32 + i) * 64 + r];
    li[i] = lpart[(h * 32 + i) * 64 + r];
    mtot = fmaxf(mtot, mi[i]);
  }
  #pragma unroll
  for (int tp = 0; tp < 4; ++tp) mtot = fmaxf(mtot, scn[tp]);
  float ltot = 0.f, od = 0.f;
  #pragma unroll
  for (int i = 0; i < 32; ++i) {
    float fct = __expf(mi[i] - mtot);
    ltot += li[i] * fct;
    od += bs2f(Opart[((size_t)(h * 32 + i) * 64 + r) * 64 + d]) * fct;
  }
  #pragma unroll
  for (int tp = 0; tp < 4; ++tp) {
    float e = __expf(scn[tp] - mtot);
    ltot += e;
    od += e * vnew[((h * 16 + b) * 4 + tp) * 64 + d];
  }
  attn[(size_t)r * 2048 + h * 64 + d] = f2bs(od / ltot);
}

// ------ Kernel 4: output projection, in-block K-split-8, reg pipeline --------
// grid 256 x 1024 threads: n-tile = bx>>1, m-half = bx&1; wave: mt=w&1, kq=w>>1.
// Per wave K=256 = 2 chunks of 128 (both prefetched up front).
__global__ __launch_bounds__(1024, 4) void k_out(
    const unsigned short* __restrict__ attn, const float* __restrict__ Wo,
    const float* __restrict__ bo, float* __restrict__ out) {
  __shared__ float red[14][16][17];
  const int n0 = (blockIdx.x >> 1) * 16;
  const int mh = blockIdx.x & 1;
  const int t = threadIdx.x, lane = t & 63, w = t >> 6;
  const int mt = w & 1, kq = w >> 1;      // kq 0..7
  const int cl = lane & 15, q = lane >> 4;
  const int rbase = mh * 32 + mt * 16;
  const unsigned short* arow = attn + (size_t)(rbase + cl) * 2048 + kq * 256 + q * 8;
  const float* brow = Wo + (size_t)(n0 + cl) * 2048 + kq * 256 + q * 8;

  s8v ab[2][4];
  f4 bb[2][8];
  auto loadc = [&](int s, int c) {
    const unsigned short* ap = arow + c * 128;
    const float* bp = brow + c * 128;
    #pragma unroll
    for (int i = 0; i < 4; ++i) {
      ab[s][i] = *reinterpret_cast<const s8v*>(ap + i * 32);
      bb[s][2 * i]     = *reinterpret_cast<const f4*>(bp + i * 32);
      bb[s][2 * i + 1] = *reinterpret_cast<const f4*>(bp + i * 32 + 4);
    }
  };
  f4 acc = fzero();
  loadc(0, 0);
  loadc(1, 1);
  #pragma unroll
  for (int c = 0; c < 2; ++c) {
    const int s = c & 1;
    #pragma unroll
    for (int i = 0; i < 4; ++i)
      acc = mfma16(ab[s][i], cvt8(bb[s][2 * i], bb[s][2 * i + 1]), acc);
  }
  if (kq) {
    #pragma unroll
    for (int rg = 0; rg < 4; ++rg) red[(kq - 1) * 2 + mt][q * 4 + rg][cl] = acc[rg];
  }
  __syncthreads();
  if (kq == 0) {
    const int c = n0 + cl;
    #pragma unroll
    for (int rg = 0; rg < 4; ++rg) {
      const int rr = q * 4 + rg;
      float v = acc[rg] + bo[c];
      #pragma unroll
      for (int j = 0; j < 7; ++j) v += red[j * 2 + mt][rr][cl];
      out[(size_t)(rbase + rr) * 2048 + c] = v;
    }
  }
}

extern "C" void kernel_launch(void* const* d_in, const int* in_sizes, int n_in,
                              void* d_out, int out_size, void* d_ws, size_t ws_size,
                              hipStream_t stream) {
  const float* hs   = (const float*)d_in[0];
  const float* pk   = (const float*)d_in[1];
  const float* pv   = (const float*)d_in[2];
  const float* mask = (const float*)d_in[3];
  const float* Wq   = (const float*)d_in[4];
  const float* bq   = (const float*)d_in[5];
  const float* Wk   = (const float*)d_in[6];
  const float* bk   = (const float*)d_in[7];
  const float* Wv   = (const float*)d_in[8];
  const float* bv   = (const float*)d_in[9];
  const float* Wo   = (const float*)d_in[10];
  const float* bo   = (const float*)d_in[11];

  float* f = (float*)d_ws;                  // ~10.8 MB used
  float* mpart = f;                         // [32][32][64]
  float* lpart = mpart + 65536;
  float* knew  = lpart + 65536;             // [32][16][4][64]
  float* vnew  = knew + 131072;
  unsigned short* Opart = (unsigned short*)(vnew + 131072);  // [32][32][64][64] bf16
  unsigned short* hsb  = Opart + 4194304;   // [64][2048] bf16
  unsigned short* qws  = hsb + 131072;      // [32][64][72] bf16
  unsigned short* attn = qws + 147456;      // [64][2048] bf16

  k_hs2bf<<<64, 256, 0, stream>>>(hs, hsb);
  k_qkvp<<<768, 512, 0, stream>>>(hsb, Wq, Wk, Wv, bq, bk, bv, qws, knew, vnew);
  k_flash<<<1024, 256, 0, stream>>>(qws, pk, pv, mask, Opart, mpart, lpart);
  k_merge<<<512, 256, 0, stream>>>(qws, knew, vnew, mask, Opart, mpart, lpart, attn);
  k_out<<<256, 1024, 0, stream>>>(attn, Wo, bo, (float*)d_out);
}

// Round 7
// 219.074 us; speedup vs baseline: 1.0297x; 1.0297x over previous
//
#include <hip/hip_runtime.h>

// OPT attention: B=16 T=4 E=2048 H=32 HD=64 P=4096 S=4100, M=B*T=64 rows.
// R7: R6 k_flash crash fix — no occupancy floor (avoid VGPR-cap spills ->
// scratch alloc inside graph capture), mask read inline (not reg-prefetched),
// u32 LDS stores. Cooperative K/V->LDS bf16 staging, P aliases K in LDS.
// MFMA mfma_f32_16x16x32_bf16: A[m=lane&15][k=quad*8+j], B[n=lane&15][k=quad*8+j],
// D col=lane&15, row=quad*4+reg (verified layouts). Output dtype: f32.

typedef float f4 __attribute__((ext_vector_type(4)));
typedef short s8v __attribute__((ext_vector_type(8)));

#define NEG_HUGE (-3.402823466e38f)

__device__ inline unsigned short f2bs(float x) {  // f32 -> bf16 bits (RNE)
  union { float f; unsigned int u; } a; a.f = x;
  unsigned int u = a.u;
  u += 0x7fffu + ((u >> 16) & 1u);
  return (unsigned short)(u >> 16);
}
__device__ inline float bs2f(unsigned short s) {
  union { unsigned int u; float f; } a; a.u = ((unsigned int)s) << 16;
  return a.f;
}
__device__ inline s8v cvt8(f4 a, f4 b) {
  s8v r;
  r[0]=(short)f2bs(a[0]); r[1]=(short)f2bs(a[1]); r[2]=(short)f2bs(a[2]); r[3]=(short)f2bs(a[3]);
  r[4]=(short)f2bs(b[0]); r[5]=(short)f2bs(b[1]); r[6]=(short)f2bs(b[2]); r[7]=(short)f2bs(b[3]);
  return r;
}
__device__ inline f4 mfma16(s8v a, s8v b, f4 c) {
  return __builtin_amdgcn_mfma_f32_16x16x32_bf16(a, b, c, 0, 0, 0);
}
__device__ inline f4 fzero() { f4 z = {0.f,0.f,0.f,0.f}; return z; }

// ---------------- Kernel 0: hs f32 -> bf16 [64][2048] ------------------------
__global__ __launch_bounds__(256) void k_hs2bf(
    const float* __restrict__ hs, unsigned short* __restrict__ hsb) {
  const int i = (blockIdx.x * 256 + threadIdx.x) * 8;   // 16384 threads
  f4 a0 = *reinterpret_cast<const f4*>(hs + i);
  f4 a1 = *reinterpret_cast<const f4*>(hs + i + 4);
  *reinterpret_cast<s8v*>(hsb + i) = cvt8(a0, a1);
}

// ---------- Kernel 1: QKV projection, in-block K-split-4, reg pipeline -------
__global__ __launch_bounds__(512, 4) void k_qkvp(
    const unsigned short* __restrict__ hsb, const float* __restrict__ Wq,
    const float* __restrict__ Wk, const float* __restrict__ Wv,
    const float* __restrict__ bq, const float* __restrict__ bk,
    const float* __restrict__ bv, unsigned short* __restrict__ qws,
    float* __restrict__ knew, float* __restrict__ vnew) {
  __shared__ float red[6][16][17];
  const int n0 = (blockIdx.x >> 1) * 16;
  const int mh = blockIdx.x & 1;
  const int p = n0 >> 11;                 // 0:q 1:k 2:v
  const int c0 = n0 & 2047;
  const float* W = (p == 0) ? Wq : (p == 1) ? Wk : Wv;
  const float* bias = (p == 0) ? bq : (p == 1) ? bk : bv;
  const int t = threadIdx.x, lane = t & 63, w = t >> 6;
  const int mt = w & 1, kq = w >> 1;
  const int cl = lane & 15, q = lane >> 4;
  const int rbase = mh * 32 + mt * 16;

  const unsigned short* arow = hsb + (rbase + cl) * 2048 + kq * 512 + q * 8;
  const float* brow = W + (size_t)(c0 + cl) * 2048 + kq * 512 + q * 8;

  s8v ab[2][4];
  f4 bb[2][8];
  auto loadc = [&](int s, int c) {
    const unsigned short* ap = arow + c * 128;
    const float* bp = brow + c * 128;
    #pragma unroll
    for (int i = 0; i < 4; ++i) {
      ab[s][i] = *reinterpret_cast<const s8v*>(ap + i * 32);
      bb[s][2 * i]     = *reinterpret_cast<const f4*>(bp + i * 32);
      bb[s][2 * i + 1] = *reinterpret_cast<const f4*>(bp + i * 32 + 4);
    }
  };
  f4 acc = fzero();
  loadc(0, 0);
  loadc(1, 1);
  #pragma unroll
  for (int c = 0; c < 4; ++c) {
    const int s = c & 1;
    s8v a0 = ab[s][0], a1 = ab[s][1], a2 = ab[s][2], a3 = ab[s][3];
    f4 b0 = bb[s][0], b1 = bb[s][1], b2 = bb[s][2], b3 = bb[s][3];
    f4 b4 = bb[s][4], b5 = bb[s][5], b6 = bb[s][6], b7 = bb[s][7];
    if (c < 2) loadc(s, c + 2);
    acc = mfma16(a0, cvt8(b0, b1), acc);
    acc = mfma16(a1, cvt8(b2, b3), acc);
    acc = mfma16(a2, cvt8(b4, b5), acc);
    acc = mfma16(a3, cvt8(b6, b7), acc);
  }
  if (kq) {
    #pragma unroll
    for (int rg = 0; rg < 4; ++rg) red[(kq - 1) * 2 + mt][q * 4 + rg][cl] = acc[rg];
  }
  __syncthreads();
  if (kq == 0) {
    const int c = c0 + cl, h = c >> 6, d = c & 63;
    #pragma unroll
    for (int rg = 0; rg < 4; ++rg) {
      const int rr = q * 4 + rg;
      const int r = rbase + rr;           // global row (b*4+t)
      const int b = r >> 2, tt = r & 3;
      float v = acc[rg] + red[mt][rr][cl] + red[2 + mt][rr][cl]
              + red[4 + mt][rr][cl] + bias[c];
      if (p == 0) {
        qws[h * 4608 + r * 72 + d] = f2bs(v * 0.125f);
      } else if (p == 1) {
        knew[((h * 16 + b) * 4 + tt) * 64 + d] = v;
      } else {
        vnew[((h * 16 + b) * 4 + tt) * 64 + d] = v;
      }
    }
  }
}

// --------- Kernel 2: flash partial attention, 128-pos chunks -----------------
// grid 1024: h = bx&31, chunk = bx>>5. Cooperative K/V -> LDS bf16 staging;
// wave w owns rows w*16..w*16+15 (in-wave softmax); P aliases K in LDS.
// No occupancy floor: LDS (37 KB) sets 4 blocks/CU; VGPR must not spill.
__global__ __launch_bounds__(256) void k_flash(
    const unsigned short* __restrict__ qws, const float* __restrict__ Kp,
    const float* __restrict__ Vp, const float* __restrict__ mask,
    unsigned short* __restrict__ Opart, float* __restrict__ mpart,
    float* __restrict__ lpart) {
  __shared__ __align__(16) unsigned short KPb[128 * 72];  // K [128][72]; later P [64][136]
  __shared__ __align__(16) unsigned short Vb[128 * 74];   // V bf16
  const int bx = blockIdx.x;
  const int h = bx & 31, cch = bx >> 5;                   // cch in [0,32)
  const int s0 = cch * 128;
  const int t = threadIdx.x, lane = t & 63, w = t >> 6;
  const int cl = lane & 15, q = lane >> 4;
  const float* Kh = Kp + (size_t)h * 4096 * 64;
  const float* Vh = Vp + (size_t)h * 4096 * 64;

  // issue all staging loads (16 x 16B per thread, fully independent)
  f4 kreg[8], vreg[8];
  #pragma unroll
  for (int i = 0; i < 8; ++i) {
    int idx = t + i * 256;                 // 0..2047 float4s
    int s = idx >> 4, d4 = (idx & 15) << 2;
    kreg[i] = *reinterpret_cast<const f4*>(Kh + (size_t)(s0 + s) * 64 + d4);
    vreg[i] = *reinterpret_cast<const f4*>(Vh + (size_t)(s0 + s) * 64 + d4);
  }
  // Q fragments for rows w*16..w*16+15
  s8v afr[2];
  #pragma unroll
  for (int k2 = 0; k2 < 2; ++k2)
    afr[k2] = *reinterpret_cast<const s8v*>(
        qws + h * 4608 + (w * 16 + cl) * 72 + k2 * 32 + q * 8);
  // write staged K/V to LDS (u32 stores)
  {
    unsigned int* K32 = reinterpret_cast<unsigned int*>(KPb);
    unsigned int* V32 = reinterpret_cast<unsigned int*>(Vb);
    #pragma unroll
    for (int i = 0; i < 8; ++i) {
      int idx = t + i * 256;
      int s = idx >> 4, d4 = (idx & 15) << 2;
      f4 kv = kreg[i];
      int uk = s * 36 + (d4 >> 1);
      K32[uk]     = (unsigned int)f2bs(kv[0]) | ((unsigned int)f2bs(kv[1]) << 16);
      K32[uk + 1] = (unsigned int)f2bs(kv[2]) | ((unsigned int)f2bs(kv[3]) << 16);
      f4 vv = vreg[i];
      int uv = s * 37 + (d4 >> 1);
      V32[uv]     = (unsigned int)f2bs(vv[0]) | ((unsigned int)f2bs(vv[1]) << 16);
      V32[uv + 1] = (unsigned int)f2bs(vv[2]) | ((unsigned int)f2bs(vv[3]) << 16);
    }
  }
  __syncthreads();   // b1: Kb + Vb ready

  // QK^T from LDS: B-frag = Kb[(ni*16+cl)][k2*32+q*8 ..+7] (b128, conflict-free)
  f4 sc[8];
  #pragma unroll
  for (int ni = 0; ni < 8; ++ni) {
    sc[ni] = fzero();
    #pragma unroll
    for (int k2 = 0; k2 < 2; ++k2) {
      s8v bf = *reinterpret_cast<const s8v*>(
          &KPb[(ni * 16 + cl) * 72 + k2 * 32 + q * 8]);
      sc[ni] = mfma16(afr[k2], bf, sc[ni]);
    }
  }
  // mask add (inline loads; L2/L3-resident) + in-wave row max
  float mx[4] = {NEG_HUGE, NEG_HUGE, NEG_HUGE, NEG_HUGE};
  #pragma unroll
  for (int rg = 0; rg < 4; ++rg) {
    const int r = w * 16 + q * 4 + rg;
    #pragma unroll
    for (int ni = 0; ni < 8; ++ni) {
      float v = fmaxf(sc[ni][rg] + mask[(size_t)r * 4100 + s0 + ni * 16 + cl],
                      NEG_HUGE);
      sc[ni][rg] = v;
      mx[rg] = fmaxf(mx[rg], v);
    }
  }
  #pragma unroll
  for (int rg = 0; rg < 4; ++rg)
    #pragma unroll
    for (int off = 1; off < 16; off <<= 1)
      mx[rg] = fmaxf(mx[rg], __shfl_xor(mx[rg], off, 64));
  // exp in regs + row sums
  float sm[4] = {0.f, 0.f, 0.f, 0.f};
  #pragma unroll
  for (int rg = 0; rg < 4; ++rg)
    #pragma unroll
    for (int ni = 0; ni < 8; ++ni) {
      float e = __expf(sc[ni][rg] - mx[rg]);
      sc[ni][rg] = e;
      sm[rg] += e;
    }
  #pragma unroll
  for (int rg = 0; rg < 4; ++rg)
    #pragma unroll
    for (int off = 1; off < 16; off <<= 1)
      sm[rg] += __shfl_xor(sm[rg], off, 64);
  if (cl == 0) {
    #pragma unroll
    for (int rg = 0; rg < 4; ++rg) {
      mpart[(h * 32 + cch) * 64 + w * 16 + q * 4 + rg] = mx[rg];
      lpart[(h * 32 + cch) * 64 + w * 16 + q * 4 + rg] = sm[rg];
    }
  }
  __syncthreads();   // b2: all waves done reading Kb -> safe to overwrite with P

  // P (bf16) -> LDS, aliased over Kb: [64][136]
  #pragma unroll
  for (int rg = 0; rg < 4; ++rg) {
    const int r = w * 16 + q * 4 + rg;
    #pragma unroll
    for (int ni = 0; ni < 8; ++ni)
      KPb[r * 136 + ni * 16 + cl] = f2bs(sc[ni][rg]);
  }
  __syncthreads();   // b3: P ready

  // PV: wave w owns d-cols w*16..w*16+15
  f4 oacc[4];
  #pragma unroll
  for (int mt = 0; mt < 4; ++mt) oacc[mt] = fzero();
  const int dcol = w * 16 + cl;
  #pragma unroll
  for (int k2 = 0; k2 < 4; ++k2) {
    const int sb = k2 * 32 + q * 8;
    s8v bf;
    #pragma unroll
    for (int j = 0; j < 8; ++j) bf[j] = (short)Vb[(sb + j) * 74 + dcol];
    #pragma unroll
    for (int mt = 0; mt < 4; ++mt) {
      s8v pa = *reinterpret_cast<const s8v*>(&KPb[(mt * 16 + cl) * 136 + sb]);
      oacc[mt] = mfma16(pa, bf, oacc[mt]);
    }
  }
  unsigned short* ob = Opart + (size_t)(h * 32 + cch) * 4096;
  #pragma unroll
  for (int mt = 0; mt < 4; ++mt)
    #pragma unroll
    for (int rg = 0; rg < 4; ++rg)
      ob[(mt * 16 + q * 4 + rg) * 64 + dcol] = f2bs(oacc[mt][rg]);
}

// ------- Kernel 3: merge 32 chunk partials + 4 new-token scores --------------
__global__ __launch_bounds__(256) void k_merge(
    const unsigned short* __restrict__ qws, const float* __restrict__ knew,
    const float* __restrict__ vnew, const float* __restrict__ mask,
    const unsigned short* __restrict__ Opart, const float* __restrict__ mpart,
    const float* __restrict__ lpart, unsigned short* __restrict__ attn) {
  const int bx = blockIdx.x;
  const int h = bx & 31, b = bx >> 5;
  const int d = threadIdx.x & 63, tt = threadIdx.x >> 6;
  const int r = b * 4 + tt;
  float qd = bs2f(qws[h * 4608 + r * 72 + d]);
  float scn[4];
  #pragma unroll
  for (int tp = 0; tp < 4; ++tp) {
    float kn = knew[((h * 16 + b) * 4 + tp) * 64 + d];
    float s = qd * kn;
    #pragma unroll
    for (int off = 32; off; off >>= 1) s += __shfl_xor(s, off, 64);
    s += mask[(size_t)r * 4100 + 4096 + tp];
    scn[tp] = fmaxf(s, NEG_HUGE);
  }
  float mi[32], li[32];
  float mtot = NEG_HUGE;
  #pragma unroll
  for (int i = 0; i < 32; ++i) {
    mi[i] = mpart[(h * 32 + i) * 64 + r];
    li[i] = lpart[(h * 32 + i) * 64 + r];
    mtot = fmaxf(mtot, mi[i]);
  }
  #pragma unroll
  for (int tp = 0; tp < 4; ++tp) mtot = fmaxf(mtot, scn[tp]);
  float ltot = 0.f, od = 0.f;
  #pragma unroll
  for (int i = 0; i < 32; ++i) {
    float fct = __expf(mi[i] - mtot);
    ltot += li[i] * fct;
    od += bs2f(Opart[((size_t)(h * 32 + i) * 64 + r) * 64 + d]) * fct;
  }
  #pragma unroll
  for (int tp = 0; tp < 4; ++tp) {
    float e = __expf(scn[tp] - mtot);
    ltot += e;
    od += e * vnew[((h * 16 + b) * 4 + tp) * 64 + d];
  }
  attn[(size_t)r * 2048 + h * 64 + d] = f2bs(od / ltot);
}

// ------ Kernel 4: output projection, in-block K-split-8, reg pipeline --------
__global__ __launch_bounds__(1024, 4) void k_out(
    const unsigned short* __restrict__ attn, const float* __restrict__ Wo,
    const float* __restrict__ bo, float* __restrict__ out) {
  __shared__ float red[14][16][17];
  const int n0 = (blockIdx.x >> 1) * 16;
  const int mh = blockIdx.x & 1;
  const int t = threadIdx.x, lane = t & 63, w = t >> 6;
  const int mt = w & 1, kq = w >> 1;      // kq 0..7
  const int cl = lane & 15, q = lane >> 4;
  const int rbase = mh * 32 + mt * 16;
  const unsigned short* arow = attn + (size_t)(rbase + cl) * 2048 + kq * 256 + q * 8;
  const float* brow = Wo + (size_t)(n0 + cl) * 2048 + kq * 256 + q * 8;

  s8v ab[2][4];
  f4 bb[2][8];
  auto loadc = [&](int s, int c) {
    const unsigned short* ap = arow + c * 128;
    const float* bp = brow + c * 128;
    #pragma unroll
    for (int i = 0; i < 4; ++i) {
      ab[s][i] = *reinterpret_cast<const s8v*>(ap + i * 32);
      bb[s][2 * i]     = *reinterpret_cast<const f4*>(bp + i * 32);
      bb[s][2 * i + 1] = *reinterpret_cast<const f4*>(bp + i * 32 + 4);
    }
  };
  f4 acc = fzero();
  loadc(0, 0);
  loadc(1, 1);
  #pragma unroll
  for (int c = 0; c < 2; ++c) {
    const int s = c & 1;
    #pragma unroll
    for (int i = 0; i < 4; ++i)
      acc = mfma16(ab[s][i], cvt8(bb[s][2 * i], bb[s][2 * i + 1]), acc);
  }
  if (kq) {
    #pragma unroll
    for (int rg = 0; rg < 4; ++rg) red[(kq - 1) * 2 + mt][q * 4 + rg][cl] = acc[rg];
  }
  __syncthreads();
  if (kq == 0) {
    const int c = n0 + cl;
    #pragma unroll
    for (int rg = 0; rg < 4; ++rg) {
      const int rr = q * 4 + rg;
      float v = acc[rg] + bo[c];
      #pragma unroll
      for (int j = 0; j < 7; ++j) v += red[j * 2 + mt][rr][cl];
      out[(size_t)(rbase + rr) * 2048 + c] = v;
    }
  }
}

extern "C" void kernel_launch(void* const* d_in, const int* in_sizes, int n_in,
                              void* d_out, int out_size, void* d_ws, size_t ws_size,
                              hipStream_t stream) {
  const float* hs   = (const float*)d_in[0];
  const float* pk   = (const float*)d_in[1];
  const float* pv   = (const float*)d_in[2];
  const float* mask = (const float*)d_in[3];
  const float* Wq   = (const float*)d_in[4];
  const float* bq   = (const float*)d_in[5];
  const float* Wk   = (const float*)d_in[6];
  const float* bk   = (const float*)d_in[7];
  const float* Wv   = (const float*)d_in[8];
  const float* bv   = (const float*)d_in[9];
  const float* Wo   = (const float*)d_in[10];
  const float* bo   = (const float*)d_in[11];

  float* f = (float*)d_ws;                  // ~10.8 MB used
  float* mpart = f;                         // [32][32][64]
  float* lpart = mpart + 65536;
  float* knew  = lpart + 65536;             // [32][16][4][64]
  float* vnew  = knew + 131072;
  unsigned short* Opart = (unsigned short*)(vnew + 131072);  // [32][32][64][64] bf16
  unsigned short* hsb  = Opart + 4194304;   // [64][2048] bf16
  unsigned short* qws  = hsb + 131072;      // [32][64][72] bf16
  unsigned short* attn = qws + 147456;      // [64][2048] bf16

  k_hs2bf<<<64, 256, 0, stream>>>(hs, hsb);
  k_qkvp<<<768, 512, 0, stream>>>(hsb, Wq, Wk, Wv, bq, bk, bv, qws, knew, vnew);
  k_flash<<<1024, 256, 0, stream>>>(qws, pk, pv, mask, Opart, mpart, lpart);
  k_merge<<<512, 256, 0, stream>>>(qws, knew, vnew, mask, Opart, mpart, lpart, attn);
  k_out<<<256, 1024, 0, stream>>>(attn, Wo, bo, (float*)d_out);
}